// Round 1
// baseline (552.709 us; speedup 1.0000x reference)
//
#include <hip/hip_runtime.h>
#include <stdint.h>

#define TT  4096   // tokens = B*S
#define HD  1024   // hidden
#define NE  8      // experts
#define ID  1024   // expert intermediate
#define SID 2816   // shared intermediate

typedef short s16x8 __attribute__((ext_vector_type(8)));
typedef float f32x4 __attribute__((ext_vector_type(4)));
typedef float f32x4v __attribute__((ext_vector_type(4)));
typedef unsigned short u16x4 __attribute__((ext_vector_type(4)));

__device__ __forceinline__ ushort f2bf(float f) {
  uint32_t u = __float_as_uint(f);
  u += 0x7FFFu + ((u >> 16) & 1u);   // RNE
  return (ushort)(u >> 16);
}

__device__ __forceinline__ void gll16(const ushort* g, ushort* l) {
  __builtin_amdgcn_global_load_lds(
      (const __attribute__((address_space(1))) void*)g,
      (__attribute__((address_space(3))) void*)l, 16, 0, 0);
}

// ---------------- fp32 -> bf16 conversion (all tensors, one launch) --------
struct CvtArgs {
  const float* src[7];
  ushort* dst[7];
  int n[7];
};

__global__ __launch_bounds__(256) void cvt_all(CvtArgs a) {
  int t = blockIdx.y;
  int i = (blockIdx.x * 256 + threadIdx.x) * 4;
  if (i >= a.n[t]) return;
  f32x4v v = *(const f32x4v*)(a.src[t] + i);
  u16x4 o;
  o.x = f2bf(v.x); o.y = f2bf(v.y); o.z = f2bf(v.z); o.w = f2bf(v.w);
  *(u16x4*)(a.dst[t] + i) = o;
}

// ---------------- router: wave per token ----------------------------------
__global__ __launch_bounds__(256) void init_k(int* cnt, int* cur) {
  if (threadIdx.x < NE) { cnt[threadIdx.x] = 0; cur[threadIdx.x] = 0; }
}

__global__ __launch_bounds__(256) void router_k(
    const float* __restrict__ X, const float* __restrict__ gw,
    const float* __restrict__ sgw, int* __restrict__ cnt,
    int* __restrict__ topki, float* __restrict__ topkw,
    float* __restrict__ sgate) {
  int t = blockIdx.x * 4 + (threadIdx.x >> 6);
  int lane = threadIdx.x & 63;
  const float* x = X + (size_t)t * HD;
  float acc[NE];
  #pragma unroll
  for (int e = 0; e < NE; e++) acc[e] = 0.f;
  float sacc = 0.f;
  for (int k = lane; k < HD; k += 64) {
    float xv = x[k];
    #pragma unroll
    for (int e = 0; e < NE; e++) acc[e] += xv * gw[e * HD + k];
    sacc += xv * sgw[k];
  }
  #pragma unroll
  for (int off = 32; off > 0; off >>= 1) {
    #pragma unroll
    for (int e = 0; e < NE; e++) acc[e] += __shfl_down(acc[e], off, 64);
    sacc += __shfl_down(sacc, off, 64);
  }
  if (lane == 0) {
    float m = acc[0];
    #pragma unroll
    for (int e = 1; e < NE; e++) m = fmaxf(m, acc[e]);
    float p[NE];
    #pragma unroll
    for (int e = 0; e < NE; e++) p[e] = __expf(acc[e] - m);
    int i1 = 0;
    #pragma unroll
    for (int e = 1; e < NE; e++) if (p[e] > p[i1]) i1 = e;
    int i2 = (i1 == 0) ? 1 : 0;
    #pragma unroll
    for (int e = 0; e < NE; e++) if (e != i1 && p[e] > p[i2]) i2 = e;
    float inv = 1.f / (p[i1] + p[i2]);   // softmax denom cancels in ratio
    topki[2 * t] = i1; topki[2 * t + 1] = i2;
    topkw[2 * t] = p[i1] * inv; topkw[2 * t + 1] = p[i2] * inv;
    atomicAdd(&cnt[i1], 1);
    atomicAdd(&cnt[i2], 1);
    sgate[t] = 1.f / (1.f + __expf(-sacc));
  }
}

__global__ void scan_k(const int* cnt, int* offs) {
  if (threadIdx.x == 0) {
    int o = 0;
    for (int e = 0; e < NE; e++) { offs[e] = o; o += cnt[e]; }
  }
}

__global__ __launch_bounds__(256) void assign_k(
    const int* __restrict__ topki, const float* __restrict__ topkw,
    const int* __restrict__ offs, int* __restrict__ cur,
    int* __restrict__ tokmap, float* __restrict__ wmap) {
  int t = blockIdx.x * 256 + threadIdx.x;
  #pragma unroll
  for (int kk = 0; kk < 2; kk++) {
    int e = topki[2 * t + kk];
    int pos = offs[e] + atomicAdd(&cur[e], 1);
    tokmap[pos] = t;
    wmap[pos] = topkw[2 * t + kk];
  }
}

// ---------------- fused gate+up GEMM with SwiGLU epilogue ------------------
// C[m][n] = X[m] . W[n]  (W stored [N][K], K-major); m97-style 128x128x32 tile
constexpr int BM = 128, BN = 128, BK = 32;

template <bool GATHER>
__global__ __launch_bounds__(256, 2) void gemm_gu(
    const ushort* __restrict__ A, const ushort* __restrict__ Wg,
    const ushort* __restrict__ Wu, ushort* __restrict__ Hout,
    const int* __restrict__ tokmap, const int* __restrict__ cnts,
    const int* __restrict__ offs, int M, int N, int K) {
  const int e = blockIdx.z;
  int cnt, seg;
  if (GATHER) { cnt = cnts[e]; seg = offs[e]; } else { cnt = M; seg = 0; }
  const int m0 = blockIdx.x * BM;
  if (m0 >= cnt) return;
  const int n0 = blockIdx.y * BN;
  const ushort* Wge = Wg + (size_t)e * N * K;
  const ushort* Wue = Wu + (size_t)e * N * K;

  __shared__ ushort lA[BM * BK];
  __shared__ ushort lBg[BN * BK];
  __shared__ ushort lBu[BN * BK];

  const int tid = threadIdx.x;
  const int wave = tid >> 6, lane = tid & 63;
  const int wm = (wave >> 1) * 64, wn = (wave & 1) * 64;

  const int ar0 = wave * 32 + (lane >> 2);
  const int ar1 = ar0 + 16;
  const int kc = (lane & 3) * 8;

  const ushort *a0p, *a1p;
  if (GATHER) {
    int m_ = m0 + ar0;
    int tk0 = (m_ < cnt) ? tokmap[seg + m_] : 0;
    m_ = m0 + ar1;
    int tk1 = (m_ < cnt) ? tokmap[seg + m_] : 0;
    a0p = A + (size_t)tk0 * K + kc;
    a1p = A + (size_t)tk1 * K + kc;
  } else {
    a0p = A + (size_t)(m0 + ar0) * K + kc;
    a1p = A + (size_t)(m0 + ar1) * K + kc;
  }
  const ushort* bg0 = Wge + (size_t)(n0 + ar0) * K + kc;
  const ushort* bg1 = Wge + (size_t)(n0 + ar1) * K + kc;
  const ushort* bu0 = Wue + (size_t)(n0 + ar0) * K + kc;
  const ushort* bu1 = Wue + (size_t)(n0 + ar1) * K + kc;

  ushort* dA0 = &lA[(wave * 32) * BK];
  ushort* dA1 = &lA[(wave * 32 + 16) * BK];
  ushort* dBg0 = &lBg[(wave * 32) * BK];
  ushort* dBg1 = &lBg[(wave * 32 + 16) * BK];
  ushort* dBu0 = &lBu[(wave * 32) * BK];
  ushort* dBu1 = &lBu[(wave * 32 + 16) * BK];

  f32x4 accG[4][4], accU[4][4];
  #pragma unroll
  for (int i = 0; i < 4; i++)
    #pragma unroll
    for (int j = 0; j < 4; j++) {
      accG[i][j] = f32x4{0.f, 0.f, 0.f, 0.f};
      accU[i][j] = f32x4{0.f, 0.f, 0.f, 0.f};
    }

  const int lr = lane & 15;
  const int lk = (lane >> 4) * 8;

  for (int k0 = 0; k0 < K; k0 += BK) {
    gll16(a0p + k0, dA0);
    gll16(a1p + k0, dA1);
    gll16(bg0 + k0, dBg0);
    gll16(bg1 + k0, dBg1);
    gll16(bu0 + k0, dBu0);
    gll16(bu1 + k0, dBu1);
    __syncthreads();
    s16x8 af[4], bgf[4], buf_[4];
    #pragma unroll
    for (int i = 0; i < 4; i++) {
      af[i]   = *(const s16x8*)&lA [(wm + i * 16 + lr) * BK + lk];
      bgf[i]  = *(const s16x8*)&lBg[(wn + i * 16 + lr) * BK + lk];
      buf_[i] = *(const s16x8*)&lBu[(wn + i * 16 + lr) * BK + lk];
    }
    #pragma unroll
    for (int i = 0; i < 4; i++)
      #pragma unroll
      for (int j = 0; j < 4; j++) {
        accG[i][j] = __builtin_amdgcn_mfma_f32_16x16x32_bf16(af[i], bgf[j], accG[i][j], 0, 0, 0);
        accU[i][j] = __builtin_amdgcn_mfma_f32_16x16x32_bf16(af[i], buf_[j], accU[i][j], 0, 0, 0);
      }
    __syncthreads();
  }

  const int lrr = (lane >> 4) * 4;
  #pragma unroll
  for (int i = 0; i < 4; i++) {
    #pragma unroll
    for (int r = 0; r < 4; r++) {
      int m = wm + i * 16 + lrr + r;
      if (m0 + m < cnt) {
        size_t row = (size_t)(seg + m0 + m) * N;
        #pragma unroll
        for (int j = 0; j < 4; j++) {
          int c = n0 + wn + j * 16 + lr;
          float g = accG[i][j][r];
          float u = accU[i][j][r];
          float s = g / (1.f + __expf(-g));   // silu
          Hout[row + c] = f2bf(s * u);
        }
      }
    }
  }
}

// ---------------- down-proj GEMM (scatter-add or gated store) --------------
template <bool GATHER>
__global__ __launch_bounds__(256, 2) void gemm_down(
    const ushort* __restrict__ A, const ushort* __restrict__ W,
    float* __restrict__ out, const int* __restrict__ tokmap,
    const float* __restrict__ wmap, const int* __restrict__ cnts,
    const int* __restrict__ offs, const float* __restrict__ sgate,
    int M, int N, int K) {
  const int e = blockIdx.z;
  int cnt, seg;
  if (GATHER) { cnt = cnts[e]; seg = offs[e]; } else { cnt = M; seg = 0; }
  const int m0 = blockIdx.x * BM;
  if (m0 >= cnt) return;
  const int n0 = blockIdx.y * BN;
  const ushort* We = W + (size_t)e * N * K;

  __shared__ ushort lA[BM * BK];
  __shared__ ushort lB[BN * BK];

  const int tid = threadIdx.x;
  const int wave = tid >> 6, lane = tid & 63;
  const int wm = (wave >> 1) * 64, wn = (wave & 1) * 64;

  const int ar0 = wave * 32 + (lane >> 2);
  const int ar1 = ar0 + 16;
  const int kc = (lane & 3) * 8;

  int r0 = m0 + ar0; if (r0 > cnt - 1) r0 = cnt - 1;
  int r1 = m0 + ar1; if (r1 > cnt - 1) r1 = cnt - 1;
  const ushort* a0p = A + (size_t)(seg + r0) * K + kc;
  const ushort* a1p = A + (size_t)(seg + r1) * K + kc;
  const ushort* b0 = We + (size_t)(n0 + ar0) * K + kc;
  const ushort* b1 = We + (size_t)(n0 + ar1) * K + kc;

  ushort* dA0 = &lA[(wave * 32) * BK];
  ushort* dA1 = &lA[(wave * 32 + 16) * BK];
  ushort* dB0 = &lB[(wave * 32) * BK];
  ushort* dB1 = &lB[(wave * 32 + 16) * BK];

  f32x4 acc[4][4];
  #pragma unroll
  for (int i = 0; i < 4; i++)
    #pragma unroll
    for (int j = 0; j < 4; j++) acc[i][j] = f32x4{0.f, 0.f, 0.f, 0.f};

  const int lr = lane & 15;
  const int lk = (lane >> 4) * 8;

  for (int k0 = 0; k0 < K; k0 += BK) {
    gll16(a0p + k0, dA0);
    gll16(a1p + k0, dA1);
    gll16(b0 + k0, dB0);
    gll16(b1 + k0, dB1);
    __syncthreads();
    s16x8 af[4], bf[4];
    #pragma unroll
    for (int i = 0; i < 4; i++) {
      af[i] = *(const s16x8*)&lA[(wm + i * 16 + lr) * BK + lk];
      bf[i] = *(const s16x8*)&lB[(wn + i * 16 + lr) * BK + lk];
    }
    #pragma unroll
    for (int i = 0; i < 4; i++)
      #pragma unroll
      for (int j = 0; j < 4; j++)
        acc[i][j] = __builtin_amdgcn_mfma_f32_16x16x32_bf16(af[i], bf[j], acc[i][j], 0, 0, 0);
    __syncthreads();
  }

  const int lrr = (lane >> 4) * 4;
  #pragma unroll
  for (int i = 0; i < 4; i++) {
    #pragma unroll
    for (int r = 0; r < 4; r++) {
      int m = wm + i * 16 + lrr + r;
      if (m0 + m < cnt) {
        if (GATHER) {
          int slot = seg + m0 + m;
          int t = tokmap[slot];
          float wv = wmap[slot];
          size_t row = (size_t)t * N;
          #pragma unroll
          for (int j = 0; j < 4; j++) {
            int c = n0 + wn + j * 16 + lr;
            atomicAdd(&out[row + c], wv * acc[i][j][r]);
          }
        } else {
          int t = m0 + m;
          float wv = sgate[t];
          size_t row = (size_t)t * N;
          #pragma unroll
          for (int j = 0; j < 4; j++) {
            int c = n0 + wn + j * 16 + lr;
            out[row + c] = wv * acc[i][j][r];
          }
        }
      }
    }
  }
}

// ---------------------------------------------------------------------------
extern "C" void kernel_launch(void* const* d_in, const int* in_sizes, int n_in,
                              void* d_out, int out_size, void* d_ws, size_t ws_size,
                              hipStream_t stream) {
  const float* hs  = (const float*)d_in[0];
  const float* gw  = (const float*)d_in[1];
  const float* wg  = (const float*)d_in[2];
  const float* wu  = (const float*)d_in[3];
  const float* wd  = (const float*)d_in[4];
  const float* swg = (const float*)d_in[5];
  const float* swu = (const float*)d_in[6];
  const float* swd = (const float*)d_in[7];
  const float* sgw = (const float*)d_in[8];
  float* out = (float*)d_out;

  uint8_t* base = (uint8_t*)d_ws;
  size_t off = 0;
  auto give = [&](size_t b) -> void* {
    void* p = base + off;
    off += (b + 255) & ~(size_t)255;
    return p;
  };
  ushort* Xb   = (ushort*)give((size_t)TT * HD * 2);
  ushort* wgB  = (ushort*)give((size_t)NE * ID * HD * 2);
  ushort* wuB  = (ushort*)give((size_t)NE * ID * HD * 2);
  ushort* wdB  = (ushort*)give((size_t)NE * HD * ID * 2);
  ushort* sgB  = (ushort*)give((size_t)SID * HD * 2);
  ushort* suB  = (ushort*)give((size_t)SID * HD * 2);
  ushort* sdB  = (ushort*)give((size_t)HD * SID * 2);
  ushort* Sbuf = (ushort*)give((size_t)TT * SID * 2);
  ushort* Hbuf = (ushort*)give((size_t)2 * TT * ID * 2);
  float* sgate = (float*)give(TT * 4);
  int* topki   = (int*)give(TT * 2 * 4);
  float* topkw = (float*)give(TT * 2 * 4);
  int* tokmap  = (int*)give(2 * TT * 4);
  float* wmap  = (float*)give(2 * TT * 4);
  int* cnt     = (int*)give(256);
  int* offs    = (int*)give(256);
  int* cur     = (int*)give(256);

  // 1. convert everything to bf16
  CvtArgs ca;
  ca.src[0] = hs;  ca.dst[0] = Xb;  ca.n[0] = TT * HD;
  ca.src[1] = wg;  ca.dst[1] = wgB; ca.n[1] = NE * ID * HD;
  ca.src[2] = wu;  ca.dst[2] = wuB; ca.n[2] = NE * ID * HD;
  ca.src[3] = wd;  ca.dst[3] = wdB; ca.n[3] = NE * HD * ID;
  ca.src[4] = swg; ca.dst[4] = sgB; ca.n[4] = SID * HD;
  ca.src[5] = swu; ca.dst[5] = suB; ca.n[5] = SID * HD;
  ca.src[6] = swd; ca.dst[6] = sdB; ca.n[6] = HD * SID;
  cvt_all<<<dim3(8192, 7), 256, 0, stream>>>(ca);

  // 2. routing
  init_k<<<1, 64, 0, stream>>>(cnt, cur);
  router_k<<<TT / 4, 256, 0, stream>>>(hs, gw, sgw, cnt, topki, topkw, sgate);
  scan_k<<<1, 1, 0, stream>>>(cnt, offs);
  assign_k<<<TT / 256, 256, 0, stream>>>(topki, topkw, offs, cur, tokmap, wmap);

  // 3. shared expert (plain store of its term into out)
  gemm_gu<false><<<dim3(TT / BM, SID / BN, 1), 256, 0, stream>>>(
      Xb, sgB, suB, Sbuf, nullptr, nullptr, nullptr, TT, SID, HD);
  gemm_down<false><<<dim3(TT / BM, HD / BN, 1), 256, 0, stream>>>(
      Sbuf, sdB, out, nullptr, nullptr, nullptr, nullptr, sgate, TT, HD, SID);

  // 4. routed experts (atomicAdd on top; stream order guarantees init done)
  gemm_gu<true><<<dim3(2 * TT / BM, ID / BN, NE), 256, 0, stream>>>(
      Xb, wgB, wuB, Hbuf, tokmap, cnt, offs, 0, ID, HD);
  gemm_down<true><<<dim3(2 * TT / BM, HD / BN, NE), 256, 0, stream>>>(
      Hbuf, wdB, out, tokmap, wmap, cnt, offs, nullptr, 0, HD, ID);
}

// Round 2
// 542.133 us; speedup vs baseline: 1.0195x; 1.0195x over previous
//
#include <hip/hip_runtime.h>
#include <stdint.h>

#define TT  4096   // tokens = B*S
#define HD  1024   // hidden
#define NE  8      // experts
#define ID  1024   // expert intermediate
#define SID 2816   // shared intermediate

typedef short s16x8 __attribute__((ext_vector_type(8)));
typedef float f32x4 __attribute__((ext_vector_type(4)));
typedef float f32x4v __attribute__((ext_vector_type(4)));
typedef unsigned short u16x4 __attribute__((ext_vector_type(4)));

__device__ __forceinline__ ushort f2bf(float f) {
  uint32_t u = __float_as_uint(f);
  u += 0x7FFFu + ((u >> 16) & 1u);   // RNE
  return (ushort)(u >> 16);
}

__device__ __forceinline__ void gll16(const ushort* g, ushort* l) {
  __builtin_amdgcn_global_load_lds(
      (const __attribute__((address_space(1))) void*)g,
      (__attribute__((address_space(3))) void*)l, 16, 0, 0);
}

// ---------------- fp32 -> bf16 conversion (all tensors, one launch) --------
struct CvtArgs {
  const float* src[7];
  ushort* dst[7];
  int n[7];
};

__global__ __launch_bounds__(256) void cvt_all(CvtArgs a) {
  int t = blockIdx.y;
  int i = (blockIdx.x * 256 + threadIdx.x) * 4;
  if (i >= a.n[t]) return;
  f32x4v v = *(const f32x4v*)(a.src[t] + i);
  u16x4 o;
  o.x = f2bf(v.x); o.y = f2bf(v.y); o.z = f2bf(v.z); o.w = f2bf(v.w);
  *(u16x4*)(a.dst[t] + i) = o;
}

// ---------------- router: wave per token ----------------------------------
__global__ __launch_bounds__(256) void init_k(int* cnt, int* cur) {
  if (threadIdx.x < NE) { cnt[threadIdx.x] = 0; cur[threadIdx.x] = 0; }
}

__global__ __launch_bounds__(256) void router_k(
    const float* __restrict__ X, const float* __restrict__ gw,
    const float* __restrict__ sgw, int* __restrict__ cnt,
    int* __restrict__ topki, float* __restrict__ topkw,
    float* __restrict__ sgate) {
  int t = blockIdx.x * 4 + (threadIdx.x >> 6);
  int lane = threadIdx.x & 63;
  const float* x = X + (size_t)t * HD;
  float acc[NE];
  #pragma unroll
  for (int e = 0; e < NE; e++) acc[e] = 0.f;
  float sacc = 0.f;
  for (int k = lane; k < HD; k += 64) {
    float xv = x[k];
    #pragma unroll
    for (int e = 0; e < NE; e++) acc[e] += xv * gw[e * HD + k];
    sacc += xv * sgw[k];
  }
  #pragma unroll
  for (int off = 32; off > 0; off >>= 1) {
    #pragma unroll
    for (int e = 0; e < NE; e++) acc[e] += __shfl_down(acc[e], off, 64);
    sacc += __shfl_down(sacc, off, 64);
  }
  if (lane == 0) {
    float m = acc[0];
    #pragma unroll
    for (int e = 1; e < NE; e++) m = fmaxf(m, acc[e]);
    float p[NE];
    #pragma unroll
    for (int e = 0; e < NE; e++) p[e] = __expf(acc[e] - m);
    int i1 = 0;
    #pragma unroll
    for (int e = 1; e < NE; e++) if (p[e] > p[i1]) i1 = e;
    int i2 = (i1 == 0) ? 1 : 0;
    #pragma unroll
    for (int e = 0; e < NE; e++) if (e != i1 && p[e] > p[i2]) i2 = e;
    float inv = 1.f / (p[i1] + p[i2]);   // softmax denom cancels in ratio
    topki[2 * t] = i1; topki[2 * t + 1] = i2;
    topkw[2 * t] = p[i1] * inv; topkw[2 * t + 1] = p[i2] * inv;
    atomicAdd(&cnt[i1], 1);
    atomicAdd(&cnt[i2], 1);
    sgate[t] = 1.f / (1.f + __expf(-sacc));
  }
}

__global__ void scan_k(const int* cnt, int* offs) {
  if (threadIdx.x == 0) {
    int o = 0;
    for (int e = 0; e < NE; e++) { offs[e] = o; o += cnt[e]; }
  }
}

__global__ __launch_bounds__(256) void assign_k(
    const int* __restrict__ topki, const float* __restrict__ topkw,
    const int* __restrict__ offs, int* __restrict__ cur,
    int* __restrict__ tokmap, float* __restrict__ wmap) {
  int t = blockIdx.x * 256 + threadIdx.x;
  #pragma unroll
  for (int kk = 0; kk < 2; kk++) {
    int e = topki[2 * t + kk];
    int pos = offs[e] + atomicAdd(&cur[e], 1);
    tokmap[pos] = t;
    wmap[pos] = topkw[2 * t + kk];
  }
}

// ---------------- fused gate+up GEMM with SwiGLU epilogue ------------------
// 2-phase double-buffered pipeline (T3-minimal): STAGE(next) -> vmcnt(L) ->
// barrier -> ds_read+MFMA(cur) -> barrier.  Never vmcnt(0) in the main loop.
constexpr int BM = 128, BN = 128, BK = 32;

template <bool GATHER>
__global__ __launch_bounds__(256, 2) void gemm_gu(
    const ushort* __restrict__ A, const ushort* __restrict__ Wg,
    const ushort* __restrict__ Wu, ushort* __restrict__ Hout,
    const int* __restrict__ tokmap, const int* __restrict__ cnts,
    const int* __restrict__ offs, int M, int N, int K) {
  const int e = blockIdx.z;
  int cnt, seg;
  if (GATHER) { cnt = cnts[e]; seg = offs[e]; } else { cnt = M; seg = 0; }
  const int m0 = blockIdx.x * BM;
  if (m0 >= cnt) return;
  const int n0 = blockIdx.y * BN;
  const ushort* Wge = Wg + (size_t)e * N * K;
  const ushort* Wue = Wu + (size_t)e * N * K;

  __shared__ ushort lA[2][BM * BK];
  __shared__ ushort lBg[2][BN * BK];
  __shared__ ushort lBu[2][BN * BK];

  const int tid = threadIdx.x;
  const int wave = tid >> 6, lane = tid & 63;
  const int wm = (wave >> 1) * 64, wn = (wave & 1) * 64;

  const int ar0 = wave * 32 + (lane >> 2);
  const int ar1 = ar0 + 16;
  const int kc = (lane & 3) * 8;

  const ushort *a0p, *a1p;
  if (GATHER) {
    int m_ = m0 + ar0;
    int tk0 = (m_ < cnt) ? tokmap[seg + m_] : 0;
    m_ = m0 + ar1;
    int tk1 = (m_ < cnt) ? tokmap[seg + m_] : 0;
    a0p = A + (size_t)tk0 * K + kc;
    a1p = A + (size_t)tk1 * K + kc;
  } else {
    a0p = A + (size_t)(m0 + ar0) * K + kc;
    a1p = A + (size_t)(m0 + ar1) * K + kc;
  }
  const ushort* bg0 = Wge + (size_t)(n0 + ar0) * K + kc;
  const ushort* bg1 = Wge + (size_t)(n0 + ar1) * K + kc;
  const ushort* bu0 = Wue + (size_t)(n0 + ar0) * K + kc;
  const ushort* bu1 = Wue + (size_t)(n0 + ar1) * K + kc;

  f32x4 accG[4][4], accU[4][4];
  #pragma unroll
  for (int i = 0; i < 4; i++)
    #pragma unroll
    for (int j = 0; j < 4; j++) {
      accG[i][j] = f32x4{0.f, 0.f, 0.f, 0.f};
      accU[i][j] = f32x4{0.f, 0.f, 0.f, 0.f};
    }

  const int lr = lane & 15;
  const int lk = (lane >> 4) * 8;
  const int w32 = wave * 32;

  auto stage = [&](int b, int k0) {
    gll16(a0p + k0, &lA[b][w32 * BK]);
    gll16(a1p + k0, &lA[b][(w32 + 16) * BK]);
    gll16(bg0 + k0, &lBg[b][w32 * BK]);
    gll16(bg1 + k0, &lBg[b][(w32 + 16) * BK]);
    gll16(bu0 + k0, &lBu[b][w32 * BK]);
    gll16(bu1 + k0, &lBu[b][(w32 + 16) * BK]);
  };

  const int nt = K / BK;
  stage(0, 0);                            // 6 loads in flight
  for (int t = 0; t < nt; t++) {
    const int cur = t & 1;
    if (t + 1 < nt) {
      stage(cur ^ 1, (t + 1) * BK);       // +6 -> 12 in flight
      asm volatile("s_waitcnt vmcnt(6)" ::: "memory");   // cur's 6 done
    } else {
      asm volatile("s_waitcnt vmcnt(0)" ::: "memory");
    }
    __builtin_amdgcn_s_barrier();

    s16x8 af[4], bgf[4], buf_[4];
    #pragma unroll
    for (int i = 0; i < 4; i++) {
      af[i]   = *(const s16x8*)&lA [cur][(wm + i * 16 + lr) * BK + lk];
      bgf[i]  = *(const s16x8*)&lBg[cur][(wn + i * 16 + lr) * BK + lk];
      buf_[i] = *(const s16x8*)&lBu[cur][(wn + i * 16 + lr) * BK + lk];
    }
    #pragma unroll
    for (int i = 0; i < 4; i++)
      #pragma unroll
      for (int j = 0; j < 4; j++) {
        accG[i][j] = __builtin_amdgcn_mfma_f32_16x16x32_bf16(af[i], bgf[j], accG[i][j], 0, 0, 0);
        accU[i][j] = __builtin_amdgcn_mfma_f32_16x16x32_bf16(af[i], buf_[j], accU[i][j], 0, 0, 0);
      }
    __builtin_amdgcn_s_barrier();         // all waves done reading cur
  }

  const int lrr = (lane >> 4) * 4;
  #pragma unroll
  for (int i = 0; i < 4; i++) {
    #pragma unroll
    for (int r = 0; r < 4; r++) {
      int m = wm + i * 16 + lrr + r;
      if (m0 + m < cnt) {
        size_t row = (size_t)(seg + m0 + m) * N;
        #pragma unroll
        for (int j = 0; j < 4; j++) {
          int c = n0 + wn + j * 16 + lr;
          float g = accG[i][j][r];
          float u = accU[i][j][r];
          float s = g / (1.f + __expf(-g));   // silu
          Hout[row + c] = f2bf(s * u);
        }
      }
    }
  }
}

// ---------------- down-proj GEMM (scatter-add or gated store) --------------
template <bool GATHER>
__global__ __launch_bounds__(256, 2) void gemm_down(
    const ushort* __restrict__ A, const ushort* __restrict__ W,
    float* __restrict__ out, const int* __restrict__ tokmap,
    const float* __restrict__ wmap, const int* __restrict__ cnts,
    const int* __restrict__ offs, const float* __restrict__ sgate,
    int M, int N, int K) {
  const int e = blockIdx.z;
  int cnt, seg;
  if (GATHER) { cnt = cnts[e]; seg = offs[e]; } else { cnt = M; seg = 0; }
  const int m0 = blockIdx.x * BM;
  if (m0 >= cnt) return;
  const int n0 = blockIdx.y * BN;
  const ushort* We = W + (size_t)e * N * K;

  __shared__ ushort lA[2][BM * BK];
  __shared__ ushort lB[2][BN * BK];

  const int tid = threadIdx.x;
  const int wave = tid >> 6, lane = tid & 63;
  const int wm = (wave >> 1) * 64, wn = (wave & 1) * 64;

  const int ar0 = wave * 32 + (lane >> 2);
  const int ar1 = ar0 + 16;
  const int kc = (lane & 3) * 8;

  int r0 = m0 + ar0; if (r0 > cnt - 1) r0 = cnt - 1;
  int r1 = m0 + ar1; if (r1 > cnt - 1) r1 = cnt - 1;
  const ushort* a0p = A + (size_t)(seg + r0) * K + kc;
  const ushort* a1p = A + (size_t)(seg + r1) * K + kc;
  const ushort* b0 = We + (size_t)(n0 + ar0) * K + kc;
  const ushort* b1 = We + (size_t)(n0 + ar1) * K + kc;

  f32x4 acc[4][4];
  #pragma unroll
  for (int i = 0; i < 4; i++)
    #pragma unroll
    for (int j = 0; j < 4; j++) acc[i][j] = f32x4{0.f, 0.f, 0.f, 0.f};

  const int lr = lane & 15;
  const int lk = (lane >> 4) * 8;
  const int w32 = wave * 32;

  auto stage = [&](int b, int k0) {
    gll16(a0p + k0, &lA[b][w32 * BK]);
    gll16(a1p + k0, &lA[b][(w32 + 16) * BK]);
    gll16(b0 + k0, &lB[b][w32 * BK]);
    gll16(b1 + k0, &lB[b][(w32 + 16) * BK]);
  };

  const int nt = K / BK;
  stage(0, 0);                            // 4 loads in flight
  for (int t = 0; t < nt; t++) {
    const int cur = t & 1;
    if (t + 1 < nt) {
      stage(cur ^ 1, (t + 1) * BK);       // +4 -> 8 in flight
      asm volatile("s_waitcnt vmcnt(4)" ::: "memory");   // cur's 4 done
    } else {
      asm volatile("s_waitcnt vmcnt(0)" ::: "memory");
    }
    __builtin_amdgcn_s_barrier();

    s16x8 af[4], bf[4];
    #pragma unroll
    for (int i = 0; i < 4; i++) {
      af[i] = *(const s16x8*)&lA[cur][(wm + i * 16 + lr) * BK + lk];
      bf[i] = *(const s16x8*)&lB[cur][(wn + i * 16 + lr) * BK + lk];
    }
    #pragma unroll
    for (int i = 0; i < 4; i++)
      #pragma unroll
      for (int j = 0; j < 4; j++)
        acc[i][j] = __builtin_amdgcn_mfma_f32_16x16x32_bf16(af[i], bf[j], acc[i][j], 0, 0, 0);
    __builtin_amdgcn_s_barrier();         // all waves done reading cur
  }

  const int lrr = (lane >> 4) * 4;
  #pragma unroll
  for (int i = 0; i < 4; i++) {
    #pragma unroll
    for (int r = 0; r < 4; r++) {
      int m = wm + i * 16 + lrr + r;
      if (m0 + m < cnt) {
        if (GATHER) {
          int slot = seg + m0 + m;
          int t = tokmap[slot];
          float wv = wmap[slot];
          size_t row = (size_t)t * N;
          #pragma unroll
          for (int j = 0; j < 4; j++) {
            int c = n0 + wn + j * 16 + lr;
            atomicAdd(&out[row + c], wv * acc[i][j][r]);
          }
        } else {
          int t = m0 + m;
          float wv = sgate[t];
          size_t row = (size_t)t * N;
          #pragma unroll
          for (int j = 0; j < 4; j++) {
            int c = n0 + wn + j * 16 + lr;
            out[row + c] = wv * acc[i][j][r];
          }
        }
      }
    }
  }
}

// ---------------------------------------------------------------------------
extern "C" void kernel_launch(void* const* d_in, const int* in_sizes, int n_in,
                              void* d_out, int out_size, void* d_ws, size_t ws_size,
                              hipStream_t stream) {
  const float* hs  = (const float*)d_in[0];
  const float* gw  = (const float*)d_in[1];
  const float* wg  = (const float*)d_in[2];
  const float* wu  = (const float*)d_in[3];
  const float* wd  = (const float*)d_in[4];
  const float* swg = (const float*)d_in[5];
  const float* swu = (const float*)d_in[6];
  const float* swd = (const float*)d_in[7];
  const float* sgw = (const float*)d_in[8];
  float* out = (float*)d_out;

  uint8_t* base = (uint8_t*)d_ws;
  size_t off = 0;
  auto give = [&](size_t b) -> void* {
    void* p = base + off;
    off += (b + 255) & ~(size_t)255;
    return p;
  };
  ushort* Xb   = (ushort*)give((size_t)TT * HD * 2);
  ushort* wgB  = (ushort*)give((size_t)NE * ID * HD * 2);
  ushort* wuB  = (ushort*)give((size_t)NE * ID * HD * 2);
  ushort* wdB  = (ushort*)give((size_t)NE * HD * ID * 2);
  ushort* sgB  = (ushort*)give((size_t)SID * HD * 2);
  ushort* suB  = (ushort*)give((size_t)SID * HD * 2);
  ushort* sdB  = (ushort*)give((size_t)HD * SID * 2);
  ushort* Sbuf = (ushort*)give((size_t)TT * SID * 2);
  ushort* Hbuf = (ushort*)give((size_t)2 * TT * ID * 2);
  float* sgate = (float*)give(TT * 4);
  int* topki   = (int*)give(TT * 2 * 4);
  float* topkw = (float*)give(TT * 2 * 4);
  int* tokmap  = (int*)give(2 * TT * 4);
  float* wmap  = (float*)give(2 * TT * 4);
  int* cnt     = (int*)give(256);
  int* offs    = (int*)give(256);
  int* cur     = (int*)give(256);

  // 1. convert everything to bf16
  CvtArgs ca;
  ca.src[0] = hs;  ca.dst[0] = Xb;  ca.n[0] = TT * HD;
  ca.src[1] = wg;  ca.dst[1] = wgB; ca.n[1] = NE * ID * HD;
  ca.src[2] = wu;  ca.dst[2] = wuB; ca.n[2] = NE * ID * HD;
  ca.src[3] = wd;  ca.dst[3] = wdB; ca.n[3] = NE * HD * ID;
  ca.src[4] = swg; ca.dst[4] = sgB; ca.n[4] = SID * HD;
  ca.src[5] = swu; ca.dst[5] = suB; ca.n[5] = SID * HD;
  ca.src[6] = swd; ca.dst[6] = sdB; ca.n[6] = HD * SID;
  cvt_all<<<dim3(8192, 7), 256, 0, stream>>>(ca);

  // 2. routing
  init_k<<<1, 64, 0, stream>>>(cnt, cur);
  router_k<<<TT / 4, 256, 0, stream>>>(hs, gw, sgw, cnt, topki, topkw, sgate);
  scan_k<<<1, 1, 0, stream>>>(cnt, offs);
  assign_k<<<TT / 256, 256, 0, stream>>>(topki, topkw, offs, cur, tokmap, wmap);

  // 3. shared expert (plain store of its term into out)
  gemm_gu<false><<<dim3(TT / BM, SID / BN, 1), 256, 0, stream>>>(
      Xb, sgB, suB, Sbuf, nullptr, nullptr, nullptr, TT, SID, HD);
  gemm_down<false><<<dim3(TT / BM, HD / BN, 1), 256, 0, stream>>>(
      Sbuf, sdB, out, nullptr, nullptr, nullptr, nullptr, sgate, TT, HD, SID);

  // 4. routed experts (atomicAdd on top; stream order guarantees init done)
  gemm_gu<true><<<dim3(2 * TT / BM, ID / BN, NE), 256, 0, stream>>>(
      Xb, wgB, wuB, Hbuf, tokmap, cnt, offs, 0, ID, HD);
  gemm_down<true><<<dim3(2 * TT / BM, HD / BN, NE), 256, 0, stream>>>(
      Hbuf, wdB, out, tokmap, wmap, cnt, offs, nullptr, 0, HD, ID);
}